// Round 1
// baseline (138.647 us; speedup 1.0000x reference)
//
#include <hip/hip_runtime.h>
#include <math.h>

// GLIF forward scan. T=64, B=128, N=2048 (derived at runtime from in_sizes).
// All recurrence math in float64 to guarantee no spike flips vs the (f64)
// numpy reference: output is 0/1, threshold 2e-2, one flip = fail.
// Expression tree matches the reference exactly:
//   I = x * (1 - be*(1 - sig(c)))
//   v = decay_v*v*(1 - ga*y) - leak_term + I - reset_w*y
//   y = (v > Vth_s) ? 1 : 0

__device__ __forceinline__ double dsig(double x) {
    return 1.0 / (1.0 + exp(-x));
}

// Precompute kernel: one thread per (t,n) element of icoef; threads with
// i < N additionally compute the per-n constants.
// ws layout (doubles): [0,N) decay_v | [N,2N) leak_term | [2N,3N) reset_w
//                      | [3N,4N) thr | [4N,5N) ga | [5N, 5N+T*N) icoef
__global__ void glif_pre_kernel(const float* __restrict__ alpha,
                                const float* __restrict__ beta,
                                const float* __restrict__ gamma,
                                const float* __restrict__ tau,
                                const float* __restrict__ Vth,
                                const float* __restrict__ leak,
                                const float* __restrict__ reVth,
                                const float* __restrict__ conduct,
                                double* __restrict__ wsd,
                                int N, int TN) {
    int i = blockIdx.x * blockDim.x + threadIdx.x;
    if (i >= TN) return;
    int n = i % N;
    double be = dsig((double)beta[n]);
    double cs = dsig((double)conduct[i]);
    wsd[5 * N + i] = 1.0 - be * (1.0 - cs);  // icoef[t][n]
    if (i < N) {
        double al     = dsig((double)alpha[i]);
        double ga     = dsig((double)gamma[i]);
        double tau_s  = dsig((double)tau[i]);
        double vth_s  = dsig((double)Vth[i]);
        double leak_s = dsig((double)leak[i]);
        double rev_s  = dsig((double)reVth[i]);
        wsd[0 * N + i] = 1.0 - al * (1.0 - tau_s);  // decay_v
        wsd[1 * N + i] = (1.0 - al) * leak_s;       // leak_term
        wsd[2 * N + i] = (1.0 - ga) * rev_s;        // reset_w
        wsd[3 * N + i] = vth_s;                     // thr
        wsd[4 * N + i] = ga;                        // ga
    }
}

// Main scan: one thread per 2 adjacent neurons (float2 global access),
// sequential loop over T. Memory-bound: 64 MB in (tx) + 64 MB out (ty).
__global__ __launch_bounds__(256) void glif_main_kernel(
        const float* __restrict__ tx,
        const double* __restrict__ wsd,
        float* __restrict__ out,
        int T, int B, int N) {
    const int half = N >> 1;
    const int idx = blockIdx.x * blockDim.x + threadIdx.x;
    if (idx >= B * half) return;
    const int b = idx / half;
    const int n = (idx - b * half) << 1;

    const double dv0 = wsd[0 * N + n], dv1 = wsd[0 * N + n + 1];
    const double lt0 = wsd[1 * N + n], lt1 = wsd[1 * N + n + 1];
    const double rw0 = wsd[2 * N + n], rw1 = wsd[2 * N + n + 1];
    const double th0 = wsd[3 * N + n], th1 = wsd[3 * N + n + 1];
    const double om_ga0 = 1.0 - wsd[4 * N + n];   // (1 - ga), exact: ga*1.0 == ga
    const double om_ga1 = 1.0 - wsd[4 * N + n + 1];
    const double* __restrict__ icp = wsd + 5 * N + n;

    double v0 = 0.0, v1 = 0.0;
    bool y0 = false, y1 = false;

    const size_t bn = (size_t)b * N + n;
    const float* txp = tx + bn;
    float* op = out + bn;
    const size_t strideTx = (size_t)B * N;

#pragma unroll 4
    for (int t = 0; t < T; ++t) {
        const float2 x = *(const float2*)txp;
        const double ic0 = icp[0], ic1 = icp[1];

        // lane 0
        const double I0 = (double)x.x * ic0;
        const double m0 = y0 ? om_ga0 : 1.0;   // (1 - ga*y), exact for y in {0,1}
        const double r0 = y0 ? rw0 : 0.0;      // reset_w*y, exact
        v0 = dv0 * v0 * m0 - lt0 + I0 - r0;
        y0 = v0 > th0;

        // lane 1
        const double I1 = (double)x.y * ic1;
        const double m1 = y1 ? om_ga1 : 1.0;
        const double r1 = y1 ? rw1 : 0.0;
        v1 = dv1 * v1 * m1 - lt1 + I1 - r1;
        y1 = v1 > th1;

        float2 o;
        o.x = y0 ? 1.0f : 0.0f;
        o.y = y1 ? 1.0f : 0.0f;
        *(float2*)op = o;

        txp += strideTx;
        op += strideTx;
        icp += N;
    }
}

// Fallback (only if ws_size is too small for the f64 tables): computes all
// sigmoids inline per thread. Slower but correct; same f64 expression tree.
__global__ __launch_bounds__(256) void glif_main_inline_kernel(
        const float* __restrict__ tx,
        const float* __restrict__ alpha,
        const float* __restrict__ beta,
        const float* __restrict__ gamma,
        const float* __restrict__ tau,
        const float* __restrict__ Vth,
        const float* __restrict__ leak,
        const float* __restrict__ reVth,
        const float* __restrict__ conduct,
        float* __restrict__ out,
        int T, int B, int N) {
    const int half = N >> 1;
    const int idx = blockIdx.x * blockDim.x + threadIdx.x;
    if (idx >= B * half) return;
    const int b = idx / half;
    const int n = (idx - b * half) << 1;

    const double al0 = dsig((double)alpha[n]), al1 = dsig((double)alpha[n + 1]);
    const double ga0 = dsig((double)gamma[n]), ga1 = dsig((double)gamma[n + 1]);
    const double be0 = dsig((double)beta[n]),  be1 = dsig((double)beta[n + 1]);
    const double ts0 = dsig((double)tau[n]),   ts1 = dsig((double)tau[n + 1]);
    const double th0 = dsig((double)Vth[n]),   th1 = dsig((double)Vth[n + 1]);
    const double ls0 = dsig((double)leak[n]),  ls1 = dsig((double)leak[n + 1]);
    const double rs0 = dsig((double)reVth[n]), rs1 = dsig((double)reVth[n + 1]);
    const double dv0 = 1.0 - al0 * (1.0 - ts0), dv1 = 1.0 - al1 * (1.0 - ts1);
    const double lt0 = (1.0 - al0) * ls0,       lt1 = (1.0 - al1) * ls1;
    const double rw0 = (1.0 - ga0) * rs0,       rw1 = (1.0 - ga1) * rs1;
    const double om_ga0 = 1.0 - ga0, om_ga1 = 1.0 - ga1;

    double v0 = 0.0, v1 = 0.0;
    bool y0 = false, y1 = false;

    const size_t bn = (size_t)b * N + n;
    const float* txp = tx + bn;
    float* op = out + bn;
    const float* cp = conduct + n;
    const size_t strideTx = (size_t)B * N;

    for (int t = 0; t < T; ++t) {
        const float2 x = *(const float2*)txp;
        const double ic0 = 1.0 - be0 * (1.0 - dsig((double)cp[0]));
        const double ic1 = 1.0 - be1 * (1.0 - dsig((double)cp[1]));

        const double I0 = (double)x.x * ic0;
        const double m0 = y0 ? om_ga0 : 1.0;
        const double r0 = y0 ? rw0 : 0.0;
        v0 = dv0 * v0 * m0 - lt0 + I0 - r0;
        y0 = v0 > th0;

        const double I1 = (double)x.y * ic1;
        const double m1 = y1 ? om_ga1 : 1.0;
        const double r1 = y1 ? rw1 : 0.0;
        v1 = dv1 * v1 * m1 - lt1 + I1 - r1;
        y1 = v1 > th1;

        float2 o;
        o.x = y0 ? 1.0f : 0.0f;
        o.y = y1 ? 1.0f : 0.0f;
        *(float2*)op = o;

        txp += strideTx;
        op += strideTx;
        cp += N;
    }
}

extern "C" void kernel_launch(void* const* d_in, const int* in_sizes, int n_in,
                              void* d_out, int out_size, void* d_ws, size_t ws_size,
                              hipStream_t stream) {
    const float* tx      = (const float*)d_in[0];
    const float* alpha   = (const float*)d_in[1];
    const float* beta    = (const float*)d_in[2];
    const float* gamma   = (const float*)d_in[3];
    const float* tau     = (const float*)d_in[4];
    const float* Vth     = (const float*)d_in[5];
    const float* leak    = (const float*)d_in[6];
    const float* reVth   = (const float*)d_in[7];
    const float* conduct = (const float*)d_in[8];
    float* out = (float*)d_out;

    const int N  = in_sizes[1];        // 2048
    const int TN = in_sizes[8];        // T*N = 131072
    const int T  = TN / N;             // 64
    const int B  = in_sizes[0] / TN;   // 128

    const int total = B * (N >> 1);    // threads in main kernel
    const int mainBlocks = (total + 255) / 256;

    const size_t needed = (size_t)(5 * N + TN) * sizeof(double);
    if (ws_size >= needed) {
        double* wsd = (double*)d_ws;
        const int preBlocks = (TN + 255) / 256;
        glif_pre_kernel<<<preBlocks, 256, 0, stream>>>(
            alpha, beta, gamma, tau, Vth, leak, reVth, conduct, wsd, N, TN);
        glif_main_kernel<<<mainBlocks, 256, 0, stream>>>(
            tx, wsd, out, T, B, N);
    } else {
        glif_main_inline_kernel<<<mainBlocks, 256, 0, stream>>>(
            tx, alpha, beta, gamma, tau, Vth, leak, reVth, conduct,
            out, T, B, N);
    }
}